// Round 11
// baseline (259.039 us; speedup 1.0000x reference)
//
#include <hip/hip_runtime.h>
#include <hip/hip_bf16.h>

// B=2, S=2048, D=1024, H=16, dk=64. fp32 in/out; bf16 MFMA compute.
// K and V^T are stored PRE-TILED in MFMA fragment order so the attention
// loop reads them with perfectly-coalesced global_load_dwordx4 (no LDS
// staging, no barriers in the K-loop).
#define SEQ 2048
#define DIM 1024
#define NH  16
#define DK  64
#define NA  (2 * SEQ * DIM)   // activation elems
#define NW  (DIM * DIM)       // weight elems
#define PSTR 72               // padded P row stride (bf16)
#define ESTR 136              // epilogue bf16 tile stride (16B-aligned rows)
#define FSTR 132              // epilogue fp32 tile stride (16B-aligned rows)
#define QSCALE 0.18033688011112042f  // 0.125 * log2(e)

typedef __attribute__((ext_vector_type(4))) float f32x4;
typedef __attribute__((ext_vector_type(8))) __bf16 bf16x8;
typedef __attribute__((ext_vector_type(4))) __bf16 bf16x4;

__device__ __forceinline__ f32x4 mfma16(bf16x8 a, bf16x8 b, f32x4 c) {
  return __builtin_amdgcn_mfma_f32_16x16x32_bf16(a, b, c, 0, 0, 0);
}
__device__ __forceinline__ void async_load16(const void* g, void* l) {
  __builtin_amdgcn_global_load_lds(
      (const __attribute__((address_space(1))) void*)g,
      (__attribute__((address_space(3))) void*)l, 16, 0, 0);
}
// XOR-swizzled 16B-chunk slot for a [rows x 64bf16] tile.
__device__ __forceinline__ int swz(int row, int chunk) {
  return row * 8 + (chunk ^ (row & 7));
}

// ---------------------------------------------------------------------------
// fp32 -> bf16 conversion + mask->bias precompute.
// grid 8193: blocks 0..6143 activations, 6144..8191 weights, 8192 bias.
// ---------------------------------------------------------------------------
__global__ __launch_bounds__(256) void cvt_kernel(
    const float* __restrict__ s0, const float* __restrict__ s1,
    const float* __restrict__ s2, const float* __restrict__ s3,
    const float* __restrict__ s4, const float* __restrict__ s5,
    const float* __restrict__ s6, const int* __restrict__ mask,
    __hip_bfloat16* __restrict__ d0, __hip_bfloat16* __restrict__ d1,
    __hip_bfloat16* __restrict__ d2, __hip_bfloat16* __restrict__ d3,
    __hip_bfloat16* __restrict__ d4, __hip_bfloat16* __restrict__ d5,
    __hip_bfloat16* __restrict__ d6, float* __restrict__ biasg) {
  const int id = blockIdx.x;
  if (id == 8192) {
    for (int i = threadIdx.x; i < 2 * SEQ; i += 256)
      biasg[i] = mask[i] ? 0.f : -1e9f;
    return;
  }
  const float* s;
  __hip_bfloat16* d;
  int bid;
  if (id < 6144) {
    int t = id >> 11;
    bid = id & 2047;
    s = (t == 0) ? s0 : ((t == 1) ? s1 : s2);
    d = (t == 0) ? d0 : ((t == 1) ? d1 : d2);
  } else {
    int t = (id - 6144) >> 9;
    bid = (id - 6144) & 511;
    s = (t == 0) ? s3 : ((t == 1) ? s4 : ((t == 2) ? s5 : s6));
    d = (t == 0) ? d3 : ((t == 1) ? d4 : ((t == 2) ? d5 : d6));
  }
  size_t i = ((size_t)bid * 256 + threadIdx.x) * 8;
  float4 a = *(const float4*)(s + i);
  float4 b = *(const float4*)(s + i + 4);
  bf16x8 v = {(__bf16)a.x, (__bf16)a.y, (__bf16)a.z, (__bf16)a.w,
              (__bf16)b.x, (__bf16)b.y, (__bf16)b.z, (__bf16)b.w};
  *(bf16x8*)(d + i) = v;
}

// ---------------------------------------------------------------------------
// Double-buffered async NT-GEMM mainloop, ONE barrier/iter (R9 version).
// lds: A0[8192] B0[8192] A1[8192] B1[8192] bf16 (64 KB). 128x128 tile.
// ---------------------------------------------------------------------------
__device__ __forceinline__ void gemm_stage(
    const __hip_bfloat16* __restrict__ X, const __hip_bfloat16* __restrict__ W,
    __hip_bfloat16* A, __hip_bfloat16* B, int m0, int n0, int k0,
    int w, int lane) {
  for (int r = 0; r < 4; ++r) {
    int cbase = r * 256 + w * 64;
    int c = cbase + lane, row = c >> 3, cs = c & 7;
    int off = cs ^ (row & 7);
    async_load16((const char*)(X + (size_t)(m0 + row) * DIM + k0) + off * 16,
                 (char*)A + cbase * 16);
    async_load16((const char*)(W + (size_t)(n0 + row) * DIM + k0) + off * 16,
                 (char*)B + cbase * 16);
  }
}

__device__ __forceinline__ void gemm_mainloop(
    const __hip_bfloat16* __restrict__ X, const __hip_bfloat16* __restrict__ W,
    __hip_bfloat16* lds, int m0, int n0, f32x4 acc[4][4]) {
  const int tid = threadIdx.x, lane = tid & 63, w = tid >> 6;
  const int quad = lane >> 4, l15 = lane & 15;
  const int wm = (w >> 1) * 64, wn = (w & 1) * 64;

  f32x4 z = {0.f, 0.f, 0.f, 0.f};
  for (int mi = 0; mi < 4; ++mi)
    for (int ni = 0; ni < 4; ++ni) acc[mi][ni] = z;

  gemm_stage(X, W, lds, lds + 8192, m0, n0, 0, w, lane);
  __syncthreads();

  for (int it = 0; it < 16; ++it) {
    __hip_bfloat16* Ac = lds + (it & 1) * 16384;
    __hip_bfloat16* Bc = Ac + 8192;
    if (it < 15) {
      __hip_bfloat16* An = lds + ((it + 1) & 1) * 16384;
      gemm_stage(X, W, An, An + 8192, m0, n0, (it + 1) * 64, w, lane);
    }
    for (int kk = 0; kk < 2; ++kk) {
      bf16x8 a[4], b[4];
      for (int mi = 0; mi < 4; ++mi)
        a[mi] = *(const bf16x8*)(Ac + swz(wm + mi * 16 + l15, kk * 4 + quad) * 8);
      for (int ni = 0; ni < 4; ++ni)
        b[ni] = *(const bf16x8*)(Bc + swz(wn + ni * 16 + l15, kk * 4 + quad) * 8);
      for (int mi = 0; mi < 4; ++mi)
        for (int ni = 0; ni < 4; ++ni)
          acc[mi][ni] = mfma16(a[mi], b[ni], acc[mi][ni]);
    }
    __syncthreads();
  }
}

// ---------------------------------------------------------------------------
// QKV projection. grid (8, 32, 3).
// z=0: q (B,H,S,dk), pre-scaled by QSCALE, LDS-coalesced store.
// z=1: k PRE-TILED k_t[bh][t][kk][mi][lane][8] (row-major LDS tile -> frag stores)
// z=2: v^T PRE-TILED vt_t[bh][t][kk][di][lane][8] (transpose LDS tile -> frag stores)
// ---------------------------------------------------------------------------
__global__ __launch_bounds__(256) void qkv_proj_kernel(
    const __hip_bfloat16* __restrict__ xq, const __hip_bfloat16* __restrict__ xk,
    const __hip_bfloat16* __restrict__ xv,
    const __hip_bfloat16* __restrict__ wq, const __hip_bfloat16* __restrict__ wk,
    const __hip_bfloat16* __restrict__ wv,
    const float* __restrict__ bq, const float* __restrict__ bk,
    const float* __restrict__ bv,
    __hip_bfloat16* __restrict__ q_ws, __hip_bfloat16* __restrict__ k_t,
    __hip_bfloat16* __restrict__ vt_t) {
  __shared__ __align__(16) __hip_bfloat16 S_lds[4 * 8192];  // 65536 B

  const int z = blockIdx.z;
  const __hip_bfloat16* X = (z == 0) ? xq : ((z == 1) ? xk : xv);
  const __hip_bfloat16* W = (z == 0) ? wq : ((z == 1) ? wk : wv);
  const float* bias = (z == 0) ? bq : ((z == 1) ? bk : bv);
  const float f = (z == 0) ? QSCALE : 1.0f;

  const int m0 = blockIdx.y * 128, n0 = blockIdx.x * 128;
  f32x4 acc[4][4];
  gemm_mainloop(X, W, S_lds, m0, n0, acc);

  const int tid = threadIdx.x, lane = tid & 63, w = tid >> 6;
  const int quad = lane >> 4, l15 = lane & 15;
  const int wm = (w >> 1) * 64, wn = (w & 1) * 64;
  const int b = m0 >> 11, tbase = (m0 & 2047) >> 6, hbase = n0 >> 6;

  if (z != 2) {
    // row-major tile
    for (int mi = 0; mi < 4; ++mi)
      for (int ni = 0; ni < 4; ++ni) {
        const float bv_ = bias[n0 + wn + ni * 16 + l15];
        for (int r = 0; r < 4; ++r)
          S_lds[(wm + mi * 16 + quad * 4 + r) * ESTR + wn + ni * 16 + l15] =
              __float2bfloat16((acc[mi][ni][r] + bv_) * f);
      }
    __syncthreads();
    if (z == 0) {
      for (int r2 = 0; r2 < 8; ++r2) {
        int c = r2 * 256 + tid;
        int row = c >> 4, j = c & 15;
        int m = m0 + row, s = m & 2047;
        int n = n0 + j * 8, h = n >> 6, d = n & 63;
        *(uint4*)(q_ws + ((size_t)(b * NH + h) * SEQ + s) * DK + d) =
            *(const uint4*)(S_lds + row * ESTR + j * 8);
      }
    } else {
      // tiled frag stores: 32 frags, wave w does 8
      for (int fi = 0; fi < 8; ++fi) {
        int fg = w * 8 + fi;
        int h_l = fg >> 4, t_l = (fg >> 3) & 1, kk = (fg >> 2) & 1, mi = fg & 3;
        uint4 vdat = *(const uint4*)(S_lds + (t_l * 64 + mi * 16 + l15) * ESTR +
                                     h_l * 64 + kk * 32 + quad * 8);
        size_t bh = (size_t)(b * NH + hbase + h_l);
        size_t off = ((((bh * 32 + tbase + t_l) * 2 + kk) * 4 + mi) * 64 + lane) * 8;
        *(uint4*)(k_t + off) = vdat;
      }
    }
  } else {
    // transpose tile T[n_local][m_local]
    for (int mi = 0; mi < 4; ++mi)
      for (int ni = 0; ni < 4; ++ni) {
        const int n_local = wn + ni * 16 + l15;
        const float bv_ = bias[n0 + n_local];
        bf16x4 tv;
        for (int r = 0; r < 4; ++r) tv[r] = (__bf16)(acc[mi][ni][r] + bv_);
        *(bf16x4*)(S_lds + n_local * ESTR + wm + mi * 16 + quad * 4) = tv;
      }
    __syncthreads();
    for (int fi = 0; fi < 8; ++fi) {
      int fg = w * 8 + fi;
      int h_l = fg >> 4, t_l = (fg >> 3) & 1, kk = (fg >> 2) & 1, di = fg & 3;
      uint4 vdat = *(const uint4*)(S_lds + (h_l * 64 + di * 16 + l15) * ESTR +
                                   t_l * 64 + kk * 32 + quad * 8);
      size_t bh = (size_t)(b * NH + hbase + h_l);
      size_t off = ((((bh * 32 + tbase + t_l) * 2 + kk) * 4 + di) * 64 + lane) * 8;
      *(uint4*)(vt_t + off) = vdat;
    }
  }
}

// ---------------------------------------------------------------------------
// Flash attention, ZERO barriers in the K-loop. grid (16, 32) x 512 threads =
// 8 waves; wave w owns q-rows [w*16, w*16+16). K/V read directly from global
// in pre-tiled fragment order (coalesced dwordx4, L1/L2-served); bias from
// global; P (wave-local) is the only LDS traffic in the loop. St = K·Q^T with
// bias in accumulator; exp2 softmax (scale folded into q); lsum via
// ones-MFMA; O^T = V^T·P^T.
// ---------------------------------------------------------------------------
__global__ __launch_bounds__(512) void attn_kernel(
    const __hip_bfloat16* __restrict__ qg, const __hip_bfloat16* __restrict__ kt,
    const __hip_bfloat16* __restrict__ vt, const int* __restrict__ mask,
    const float* __restrict__ biasg, __hip_bfloat16* __restrict__ ctx) {
  __shared__ __align__(16) __hip_bfloat16 P_lds[128 * PSTR];  // 18.4 KB

  const int tid = threadIdx.x, lane = tid & 63, w = tid >> 6;
  const int quad = lane >> 4, l15 = lane & 15;
  const int bh = blockIdx.y, b = bh >> 4, h = bh & 15;
  const int q0 = blockIdx.x * 128;
  const size_t head = (size_t)bh * SEQ * DK;

  // Q fragments direct from global (once)
  bf16x8 qf[2];
  for (int kk = 0; kk < 2; ++kk)
    qf[kk] = *(const bf16x8*)(qg + head + (size_t)(q0 + w * 16 + l15) * DK +
                              kk * 32 + quad * 8);
  const int qmv = mask[b * SEQ + q0 + w * 16 + l15];
  const float* bias_b = biasg + b * SEQ;

  const bf16x8 ones = {(__bf16)1.f, (__bf16)1.f, (__bf16)1.f, (__bf16)1.f,
                       (__bf16)1.f, (__bf16)1.f, (__bf16)1.f, (__bf16)1.f};
  f32x4 z = {0.f, 0.f, 0.f, 0.f};
  f32x4 o_acc[4];
  for (int di = 0; di < 4; ++di) o_acc[di] = z;
  f32x4 o_sum = z;

  const size_t tb = (size_t)bh * 32;  // tile base for this head

  for (int t = 0; t < 32; ++t) {
    // St = K Q^T, bias in accumulator init (global broadcast loads)
    f32x4 s_acc[4];
    for (int mi = 0; mi < 4; ++mi)
      s_acc[mi] = *(const f32x4*)(bias_b + t * 64 + mi * 16 + quad * 4);
    for (int kk = 0; kk < 2; ++kk) {
      bf16x8 ak[4];
      for (int mi = 0; mi < 4; ++mi)
        ak[mi] = *(const bf16x8*)(kt + ((((tb + t) * 2 + kk) * 4 + mi) * 64 + lane) * 8);
      for (int mi = 0; mi < 4; ++mi)
        s_acc[mi] = mfma16(ak[mi], qf[kk], s_acc[mi]);
    }

    // qrow select + exp2 + P[qrow][key] b64 store (wave-local, no barrier)
    for (int mi = 0; mi < 4; ++mi) {
      bf16x4 pk;
      for (int r = 0; r < 4; ++r) {
        float s2 = qmv ? s_acc[mi][r] : 0.f;
        pk[r] = (__bf16)__builtin_amdgcn_exp2f(s2);
      }
      *(bf16x4*)(P_lds + (w * 16 + l15) * PSTR + mi * 16 + quad * 4) = pk;
    }

    // O^T += V^T P^T ; row-sums via ones-MFMA (V frags direct from global)
    for (int kk = 0; kk < 2; ++kk) {
      bf16x8 bp = *(const bf16x8*)(P_lds + (w * 16 + l15) * PSTR + kk * 32 + quad * 8);
      bf16x8 av[4];
      for (int di = 0; di < 4; ++di)
        av[di] = *(const bf16x8*)(vt + ((((tb + t) * 2 + kk) * 4 + di) * 64 + lane) * 8);
      for (int di = 0; di < 4; ++di)
        o_acc[di] = mfma16(av[di], bp, o_acc[di]);
      o_sum = mfma16(ones, bp, o_sum);
    }
  }

  const float inv = 1.f / o_sum[0];

  // O^T -> LDS [qrow][d], then coalesced ctx store
  for (int di = 0; di < 4; ++di) {
    bf16x4 ov;
    for (int r = 0; r < 4; ++r) ov[r] = (__bf16)(o_acc[di][r] * inv);
    *(bf16x4*)(P_lds + (w * 16 + l15) * PSTR + di * 16 + quad * 4) = ov;
  }
  __syncthreads();
  for (int r = 0; r < 2; ++r) {
    int c = r * 512 + tid, row = c >> 3, off = c & 7;
    *(uint4*)(ctx + (size_t)(b * SEQ + q0 + row) * DIM + h * DK + off * 8) =
        *(const uint4*)(P_lds + row * PSTR + off * 8);
  }
}

// ---------------------------------------------------------------------------
// Output projection: out = ctx @ wo^T + bo (bf16 in, fp32 out). grid (8,32).
// Single-pass LDS-coalesced fp32 epilogue.
// ---------------------------------------------------------------------------
__global__ __launch_bounds__(256) void out_proj_kernel(
    const __hip_bfloat16* __restrict__ ctx, const __hip_bfloat16* __restrict__ wo,
    const float* __restrict__ bo, float* __restrict__ out) {
  __shared__ __align__(16) char S_raw[128 * FSTR * 4];  // 67584 B (>= 65536)
  __hip_bfloat16* S_lds = (__hip_bfloat16*)S_raw;

  const int m0 = blockIdx.y * 128, n0 = blockIdx.x * 128;
  f32x4 acc[4][4];
  gemm_mainloop(ctx, wo, S_lds, m0, n0, acc);

  const int tid = threadIdx.x, lane = tid & 63, w = tid >> 6;
  const int quad = lane >> 4, l15 = lane & 15;
  const int wm = (w >> 1) * 64, wn = (w & 1) * 64;
  float* epi = (float*)S_raw;

  for (int mi = 0; mi < 4; ++mi)
    for (int ni = 0; ni < 4; ++ni) {
      const float bv_ = bo[n0 + wn + ni * 16 + l15];
      for (int r = 0; r < 4; ++r)
        epi[(wm + mi * 16 + quad * 4 + r) * FSTR + wn + ni * 16 + l15] =
            acc[mi][ni][r] + bv_;
    }
  __syncthreads();
  for (int r2 = 0; r2 < 16; ++r2) {
    int c = r2 * 256 + tid;
    int row = c >> 5, j = c & 31;
    *(float4*)(out + (size_t)(m0 + row) * DIM + n0 + j * 4) =
        *(const float4*)(epi + row * FSTR + j * 4);
  }
}

extern "C" void kernel_launch(void* const* d_in, const int* in_sizes, int n_in,
                              void* d_out, int out_size, void* d_ws, size_t ws_size,
                              hipStream_t stream) {
  const float* query = (const float*)d_in[0];
  const float* key   = (const float*)d_in[1];
  const float* value = (const float*)d_in[2];
  const int*   mask  = (const int*)d_in[3];
  const float* wq = (const float*)d_in[4];
  const float* bq = (const float*)d_in[5];
  const float* wk = (const float*)d_in[6];
  const float* bk = (const float*)d_in[7];
  const float* wv = (const float*)d_in[8];
  const float* bv = (const float*)d_in[9];
  const float* wo = (const float*)d_in[10];
  const float* bo = (const float*)d_in[11];
  float* out = (float*)d_out;

  char* ws = (char*)d_ws;
  const size_t SZA = (size_t)NA * 2;  // 8 MiB bf16 activation
  const size_t SZW = (size_t)NW * 2;  // 2 MiB bf16 weight
  __hip_bfloat16* xq  = (__hip_bfloat16*)(ws);
  __hip_bfloat16* xk  = (__hip_bfloat16*)(ws + SZA);
  __hip_bfloat16* xv  = (__hip_bfloat16*)(ws + 2 * SZA);
  __hip_bfloat16* wqb = (__hip_bfloat16*)(ws + 3 * SZA);
  __hip_bfloat16* wkb = (__hip_bfloat16*)(ws + 3 * SZA + SZW);
  __hip_bfloat16* wvb = (__hip_bfloat16*)(ws + 3 * SZA + 2 * SZW);
  __hip_bfloat16* wob = (__hip_bfloat16*)(ws + 3 * SZA + 3 * SZW);
  __hip_bfloat16* q_ws = (__hip_bfloat16*)(ws + 3 * SZA + 4 * SZW);
  __hip_bfloat16* k_t  = (__hip_bfloat16*)(ws + 4 * SZA + 4 * SZW);
  __hip_bfloat16* vt_t = (__hip_bfloat16*)(ws + 5 * SZA + 4 * SZW);
  float* biasg = (float*)(ws + 6 * SZA + 4 * SZW);  // 16 KB
  __hip_bfloat16* ctx_ws = xq;  // xq dead after qkv_proj

  cvt_kernel<<<dim3(8193), dim3(256), 0, stream>>>(
      query, key, value, wq, wk, wv, wo, mask,
      xq, xk, xv, wqb, wkb, wvb, wob, biasg);
  qkv_proj_kernel<<<dim3(8, 32, 3), dim3(256), 0, stream>>>(
      xq, xk, xv, wqb, wkb, wvb, bq, bk, bv, q_ws, k_t, vt_t);
  attn_kernel<<<dim3(16, 32), dim3(512), 0, stream>>>(
      q_ws, k_t, vt_t, mask, biasg, ctx_ws);
  out_proj_kernel<<<dim3(8, 32), dim3(256), 0, stream>>>(ctx_ws, wob, bo, out);
}

// Round 12
// 223.347 us; speedup vs baseline: 1.1598x; 1.1598x over previous
//
#include <hip/hip_runtime.h>
#include <hip/hip_bf16.h>

// B=2, S=2048, D=1024, H=16, dk=64. fp32 in/out; bf16 MFMA compute.
#define SEQ 2048
#define DIM 1024
#define NH  16
#define DK  64
#define NA  (2 * SEQ * DIM)   // activation elems
#define NW  (DIM * DIM)       // weight elems
#define PSTR 72               // padded P row stride (bf16)
#define ESTR 136              // epilogue bf16 tile stride (16B-aligned rows)
#define FSTR 132              // epilogue fp32 tile stride (16B-aligned rows)
#define QSCALE 0.18033688011112042f  // 0.125 * log2(e)

typedef __attribute__((ext_vector_type(4))) float f32x4;
typedef __attribute__((ext_vector_type(8))) __bf16 bf16x8;
typedef __attribute__((ext_vector_type(4))) __bf16 bf16x4;

__device__ __forceinline__ f32x4 mfma16(bf16x8 a, bf16x8 b, f32x4 c) {
  return __builtin_amdgcn_mfma_f32_16x16x32_bf16(a, b, c, 0, 0, 0);
}
__device__ __forceinline__ void async_load16(const void* g, void* l) {
  __builtin_amdgcn_global_load_lds(
      (const __attribute__((address_space(1))) void*)g,
      (__attribute__((address_space(3))) void*)l, 16, 0, 0);
}
// XOR-swizzled 16B-chunk slot for a [rows x 64bf16] tile.
__device__ __forceinline__ int swz(int row, int chunk) {
  return row * 8 + (chunk ^ (row & 7));
}

// ---------------------------------------------------------------------------
// fp32 -> bf16 conversion + mask->bias precompute. grid 8193.
// ---------------------------------------------------------------------------
__global__ __launch_bounds__(256) void cvt_kernel(
    const float* __restrict__ s0, const float* __restrict__ s1,
    const float* __restrict__ s2, const float* __restrict__ s3,
    const float* __restrict__ s4, const float* __restrict__ s5,
    const float* __restrict__ s6, const int* __restrict__ mask,
    __hip_bfloat16* __restrict__ d0, __hip_bfloat16* __restrict__ d1,
    __hip_bfloat16* __restrict__ d2, __hip_bfloat16* __restrict__ d3,
    __hip_bfloat16* __restrict__ d4, __hip_bfloat16* __restrict__ d5,
    __hip_bfloat16* __restrict__ d6, float* __restrict__ biasg) {
  const int id = blockIdx.x;
  if (id == 8192) {
    for (int i = threadIdx.x; i < 2 * SEQ; i += 256)
      biasg[i] = mask[i] ? 0.f : -1e9f;
    return;
  }
  const float* s;
  __hip_bfloat16* d;
  int bid;
  if (id < 6144) {
    int t = id >> 11;
    bid = id & 2047;
    s = (t == 0) ? s0 : ((t == 1) ? s1 : s2);
    d = (t == 0) ? d0 : ((t == 1) ? d1 : d2);
  } else {
    int t = (id - 6144) >> 9;
    bid = (id - 6144) & 511;
    s = (t == 0) ? s3 : ((t == 1) ? s4 : ((t == 2) ? s5 : s6));
    d = (t == 0) ? d3 : ((t == 1) ? d4 : ((t == 2) ? d5 : d6));
  }
  size_t i = ((size_t)bid * 256 + threadIdx.x) * 8;
  float4 a = *(const float4*)(s + i);
  float4 b = *(const float4*)(s + i + 4);
  bf16x8 v = {(__bf16)a.x, (__bf16)a.y, (__bf16)a.z, (__bf16)a.w,
              (__bf16)b.x, (__bf16)b.y, (__bf16)b.z, (__bf16)b.w};
  *(bf16x8*)(d + i) = v;
}

// ---------------------------------------------------------------------------
// Double-buffered async NT-GEMM mainloop, ONE barrier/iter (R9 version).
// ---------------------------------------------------------------------------
__device__ __forceinline__ void gemm_stage(
    const __hip_bfloat16* __restrict__ X, const __hip_bfloat16* __restrict__ W,
    __hip_bfloat16* A, __hip_bfloat16* B, int m0, int n0, int k0,
    int w, int lane) {
  for (int r = 0; r < 4; ++r) {
    int cbase = r * 256 + w * 64;
    int c = cbase + lane, row = c >> 3, cs = c & 7;
    int off = cs ^ (row & 7);
    async_load16((const char*)(X + (size_t)(m0 + row) * DIM + k0) + off * 16,
                 (char*)A + cbase * 16);
    async_load16((const char*)(W + (size_t)(n0 + row) * DIM + k0) + off * 16,
                 (char*)B + cbase * 16);
  }
}

__device__ __forceinline__ void gemm_mainloop(
    const __hip_bfloat16* __restrict__ X, const __hip_bfloat16* __restrict__ W,
    __hip_bfloat16* lds, int m0, int n0, f32x4 acc[4][4]) {
  const int tid = threadIdx.x, lane = tid & 63, w = tid >> 6;
  const int quad = lane >> 4, l15 = lane & 15;
  const int wm = (w >> 1) * 64, wn = (w & 1) * 64;

  f32x4 z = {0.f, 0.f, 0.f, 0.f};
  for (int mi = 0; mi < 4; ++mi)
    for (int ni = 0; ni < 4; ++ni) acc[mi][ni] = z;

  gemm_stage(X, W, lds, lds + 8192, m0, n0, 0, w, lane);
  __syncthreads();

  for (int it = 0; it < 16; ++it) {
    __hip_bfloat16* Ac = lds + (it & 1) * 16384;
    __hip_bfloat16* Bc = Ac + 8192;
    if (it < 15) {
      __hip_bfloat16* An = lds + ((it + 1) & 1) * 16384;
      gemm_stage(X, W, An, An + 8192, m0, n0, (it + 1) * 64, w, lane);
    }
    for (int kk = 0; kk < 2; ++kk) {
      bf16x8 a[4], b[4];
      for (int mi = 0; mi < 4; ++mi)
        a[mi] = *(const bf16x8*)(Ac + swz(wm + mi * 16 + l15, kk * 4 + quad) * 8);
      for (int ni = 0; ni < 4; ++ni)
        b[ni] = *(const bf16x8*)(Bc + swz(wn + ni * 16 + l15, kk * 4 + quad) * 8);
      for (int mi = 0; mi < 4; ++mi)
        for (int ni = 0; ni < 4; ++ni)
          acc[mi][ni] = mfma16(a[mi], b[ni], acc[mi][ni]);
    }
    __syncthreads();
  }
}

// ---------------------------------------------------------------------------
// QKV projection (R9 layouts). grid (8, 32, 3). q scaled by QSCALE, (B,H,S,dk);
// k (B,H,S,dk); v transposed (B,H,dk,S).
// ---------------------------------------------------------------------------
__global__ __launch_bounds__(256) void qkv_proj_kernel(
    const __hip_bfloat16* __restrict__ xq, const __hip_bfloat16* __restrict__ xk,
    const __hip_bfloat16* __restrict__ xv,
    const __hip_bfloat16* __restrict__ wq, const __hip_bfloat16* __restrict__ wk,
    const __hip_bfloat16* __restrict__ wv,
    const float* __restrict__ bq, const float* __restrict__ bk,
    const float* __restrict__ bv,
    __hip_bfloat16* __restrict__ q_ws, __hip_bfloat16* __restrict__ k_ws,
    __hip_bfloat16* __restrict__ vt_ws) {
  __shared__ __align__(16) __hip_bfloat16 S_lds[4 * 8192];  // 65536 B

  const int z = blockIdx.z;
  const __hip_bfloat16* X = (z == 0) ? xq : ((z == 1) ? xk : xv);
  const __hip_bfloat16* W = (z == 0) ? wq : ((z == 1) ? wk : wv);
  const float* bias = (z == 0) ? bq : ((z == 1) ? bk : bv);
  const float f = (z == 0) ? QSCALE : 1.0f;

  const int m0 = blockIdx.y * 128, n0 = blockIdx.x * 128;
  f32x4 acc[4][4];
  gemm_mainloop(X, W, S_lds, m0, n0, acc);

  const int tid = threadIdx.x, lane = tid & 63, w = tid >> 6;
  const int quad = lane >> 4, l15 = lane & 15;
  const int wm = (w >> 1) * 64, wn = (w & 1) * 64;

  if (z != 2) {
    __hip_bfloat16* out = (z == 0) ? q_ws : k_ws;
    for (int mi = 0; mi < 4; ++mi)
      for (int ni = 0; ni < 4; ++ni) {
        const float bv_ = bias[n0 + wn + ni * 16 + l15];
        for (int r = 0; r < 4; ++r)
          S_lds[(wm + mi * 16 + quad * 4 + r) * ESTR + wn + ni * 16 + l15] =
              __float2bfloat16((acc[mi][ni][r] + bv_) * f);
      }
    __syncthreads();
    for (int r2 = 0; r2 < 8; ++r2) {
      int c = r2 * 256 + tid;
      int row = c >> 4, j = c & 15;
      int m = m0 + row, b = m >> 11, s = m & 2047;
      int n = n0 + j * 8, h = n >> 6, d = n & 63;
      *(uint4*)(out + ((size_t)(b * NH + h) * SEQ + s) * DK + d) =
          *(const uint4*)(S_lds + row * ESTR + j * 8);
    }
  } else {
    for (int mi = 0; mi < 4; ++mi)
      for (int ni = 0; ni < 4; ++ni) {
        const int n_local = wn + ni * 16 + l15;
        const float bv_ = bias[n0 + n_local];
        bf16x4 tv;
        for (int r = 0; r < 4; ++r) tv[r] = (__bf16)(acc[mi][ni][r] + bv_);
        *(bf16x4*)(S_lds + n_local * ESTR + wm + mi * 16 + quad * 4) = tv;
      }
    __syncthreads();
    const int b = m0 >> 11, s_base = m0 & 2047;
    for (int r2 = 0; r2 < 8; ++r2) {
      int c2 = r2 * 256 + tid;
      int nrow = c2 >> 4, moff = (c2 & 15) * 8;
      int n = n0 + nrow, h = n >> 6, d = n & 63;
      *(uint4*)(vt_ws + ((size_t)(b * NH + h) * DK + d) * SEQ + s_base + moff) =
          *(const uint4*)(S_lds + nrow * ESTR + moff);
    }
  }
}

// ---------------------------------------------------------------------------
// Flash attention, k-split. grid (16, 32) x 512 threads = 8 waves.
// Wave w = 2g+h owns q-rows [g*32, g*32+32) and key half h (tiles h*16+u).
// Each k-tile is read by only 4 waves (vs 8 in R9) -> K/V fragment LDS
// traffic per CU halves. No running max (exp2 domain) -> key-split partials
// combine ADDITIVELY at the end via an fp32 LDS reduction (exact).
// Bias/Q/mask from global. 16 iters x 2 barriers (single-buffered K/V).
// ---------------------------------------------------------------------------
__global__ __launch_bounds__(512, 4) void attn_kernel(
    const __hip_bfloat16* __restrict__ qg, const __hip_bfloat16* __restrict__ kg,
    const __hip_bfloat16* __restrict__ vtg, const int* __restrict__ mask,
    const float* __restrict__ biasg, __hip_bfloat16* __restrict__ ctx) {
  __shared__ __align__(16) char KV_raw[32768];   // K[2]/V[2] tiles; later fp32 scratch
  __shared__ __align__(16) __hip_bfloat16 P_lds[256 * PSTR];  // per-wave P (36.9 KB)
  __shared__ float osum_lds[4][32];

  __hip_bfloat16* K_lds = (__hip_bfloat16*)KV_raw;            // [2][4096]
  __hip_bfloat16* V_lds = (__hip_bfloat16*)(KV_raw + 16384);  // [2][4096]

  const int tid = threadIdx.x, lane = tid & 63, w = tid >> 6;
  const int quad = lane >> 4, l15 = lane & 15;
  const int g = w >> 1, half = w & 1;
  const int bh = blockIdx.y, b = bh >> 4, h = bh & 15;
  const int q0 = blockIdx.x * 128;
  const size_t head = (size_t)bh * SEQ * DK;
  const size_t vthead = (size_t)bh * DK * SEQ;

  // Q fragments + q-mask direct from global (once)
  bf16x8 qf[2][2];  // [kk][ni]
  for (int kk = 0; kk < 2; ++kk)
    for (int ni = 0; ni < 2; ++ni)
      qf[kk][ni] = *(const bf16x8*)(qg + head +
          (size_t)(q0 + g * 32 + ni * 16 + l15) * DK + kk * 32 + quad * 8);
  int qmv[2];
  for (int ni = 0; ni < 2; ++ni)
    qmv[ni] = mask[b * SEQ + q0 + g * 32 + ni * 16 + l15];
  const float* bias_b = biasg + b * SEQ;

  const bf16x8 ones = {(__bf16)1.f, (__bf16)1.f, (__bf16)1.f, (__bf16)1.f,
                       (__bf16)1.f, (__bf16)1.f, (__bf16)1.f, (__bf16)1.f};
  f32x4 z = {0.f, 0.f, 0.f, 0.f};
  f32x4 o_acc[2][4];  // [ni][di]: qrow = ni*16+l15, d = di*16+quad*4+r
  for (int ni = 0; ni < 2; ++ni)
    for (int di = 0; di < 4; ++di) o_acc[ni][di] = z;
  f32x4 o_sum[2] = {z, z};
  __hip_bfloat16* P_w = P_lds + w * 32 * PSTR;

  for (int u = 0; u < 16; ++u) {
    // stage 4 tiles (K half0/1, V half0/1), 32 KB, 4 chunks/thread
    {
      int row = tid >> 3, cs = tid & 7;
      int off = cs ^ (row & 7);
      // K halves
      async_load16((const char*)(kg + head + (size_t)(u * 64 + row) * DK) + off * 16,
                   (char*)K_lds + tid * 16);
      async_load16((const char*)(kg + head + (size_t)((16 + u) * 64 + row) * DK) + off * 16,
                   (char*)(K_lds + 4096) + tid * 16);
      // V^T halves
      async_load16((const char*)(vtg + vthead + (size_t)row * SEQ + u * 64) + off * 16,
                   (char*)V_lds + tid * 16);
      async_load16((const char*)(vtg + vthead + (size_t)row * SEQ + (16 + u) * 64) + off * 16,
                   (char*)(V_lds + 4096) + tid * 16);
    }
    __syncthreads();  // staging visible

    const __hip_bfloat16* Kc = K_lds + half * 4096;
    const __hip_bfloat16* Vc = V_lds + half * 4096;
    const int kbase = (half * 16 + u) * 64;

    // St = K Q^T, bias in accumulator init
    f32x4 s_acc[4][2];
    for (int mi = 0; mi < 4; ++mi) {
      f32x4 kb = *(const f32x4*)(bias_b + kbase + mi * 16 + quad * 4);
      for (int ni = 0; ni < 2; ++ni) s_acc[mi][ni] = kb;
    }
    for (int kk = 0; kk < 2; ++kk) {
      bf16x8 ak[4];
      for (int mi = 0; mi < 4; ++mi)
        ak[mi] = *(const bf16x8*)(Kc + swz(mi * 16 + l15, kk * 4 + quad) * 8);
      for (int mi = 0; mi < 4; ++mi)
        for (int ni = 0; ni < 2; ++ni)
          s_acc[mi][ni] = mfma16(ak[mi], qf[kk][ni], s_acc[mi][ni]);
    }

    // qrow select + exp2 + P store (wave-local)
    for (int mi = 0; mi < 4; ++mi)
      for (int ni = 0; ni < 2; ++ni) {
        bf16x4 pk;
        for (int r = 0; r < 4; ++r) {
          float s2 = qmv[ni] ? s_acc[mi][ni][r] : 0.f;
          pk[r] = (__bf16)__builtin_amdgcn_exp2f(s2);
        }
        *(bf16x4*)(P_w + (ni * 16 + l15) * PSTR + mi * 16 + quad * 4) = pk;
      }

    // O^T += V^T P^T ; row-sums via ones-MFMA
    for (int kk = 0; kk < 2; ++kk) {
      bf16x8 av[4], bp[2];
      for (int di = 0; di < 4; ++di)
        av[di] = *(const bf16x8*)(Vc + swz(di * 16 + l15, kk * 4 + quad) * 8);
      for (int ni = 0; ni < 2; ++ni)
        bp[ni] = *(const bf16x8*)(P_w + (ni * 16 + l15) * PSTR + kk * 32 + quad * 8);
      for (int ni = 0; ni < 2; ++ni) {
        for (int di = 0; di < 4; ++di)
          o_acc[ni][di] = mfma16(av[di], bp[ni], o_acc[ni][di]);
        o_sum[ni] = mfma16(ones, bp[ni], o_sum[ni]);
      }
    }
    __syncthreads();  // all waves done with K/V before restage
  }

  // ---- combine halves (additive; exact) ----
  float* scr = (float*)KV_raw;  // 8192 f32 (= 128 rows x 16 f32x4-chunks)
  if (half == 0) {
    for (int ni = 0; ni < 2; ++ni)
      for (int di = 0; di < 4; ++di) {
        int row = g * 32 + ni * 16 + l15, ch = di * 4 + quad;
        *(f32x4*)(scr + (row * 16 + (ch ^ (row & 7))) * 4) = o_acc[ni][di];
      }
    if (quad == 0)
      for (int ni = 0; ni < 2; ++ni)
        osum_lds[g][ni * 16 + l15] = o_sum[ni][0];
  }
  __syncthreads();
  if (half == 1) {
    float inv[2];
    for (int ni = 0; ni < 2; ++ni)
      inv[ni] = 1.f / (o_sum[ni][0] + osum_lds[g][ni * 16 + l15]);
    for (int ni = 0; ni < 2; ++ni)
      for (int di = 0; di < 4; ++di) {
        int row = g * 32 + ni * 16 + l15, ch = di * 4 + quad;
        f32x4 part = *(const f32x4*)(scr + (row * 16 + (ch ^ (row & 7))) * 4);
        bf16x4 ov;
        for (int r = 0; r < 4; ++r)
          ov[r] = (__bf16)((o_acc[ni][di][r] + part[r]) * inv[ni]);
        *(bf16x4*)(P_lds + row * PSTR + di * 16 + quad * 4) = ov;
      }
  }
  __syncthreads();
  // coalesced ctx store: 128 rows x 8 chunks
  for (int r = 0; r < 2; ++r) {
    int c = r * 512 + tid, row = c >> 3, off = c & 7;
    *(uint4*)(ctx + (size_t)(b * SEQ + q0 + row) * DIM + h * DK + off * 8) =
        *(const uint4*)(P_lds + row * PSTR + off * 8);
  }
}

// ---------------------------------------------------------------------------
// Output projection: out = ctx @ wo^T + bo (bf16 in, fp32 out). grid (8,32).
// ---------------------------------------------------------------------------
__global__ __launch_bounds__(256) void out_proj_kernel(
    const __hip_bfloat16* __restrict__ ctx, const __hip_bfloat16* __restrict__ wo,
    const float* __restrict__ bo, float* __restrict__ out) {
  __shared__ __align__(16) char S_raw[128 * FSTR * 4];  // 67584 B (>= 65536)
  __hip_bfloat16* S_lds = (__hip_bfloat16*)S_raw;

  const int m0 = blockIdx.y * 128, n0 = blockIdx.x * 128;
  f32x4 acc[4][4];
  gemm_mainloop(ctx, wo, S_lds, m0, n0, acc);

  const int tid = threadIdx.x, lane = tid & 63, w = tid >> 6;
  const int quad = lane >> 4, l15 = lane & 15;
  const int wm = (w >> 1) * 64, wn = (w & 1) * 64;
  float* epi = (float*)S_raw;

  for (int mi = 0; mi < 4; ++mi)
    for (int ni = 0; ni < 4; ++ni) {
      const float bv_ = bo[n0 + wn + ni * 16 + l15];
      for (int r = 0; r < 4; ++r)
        epi[(wm + mi * 16 + quad * 4 + r) * FSTR + wn + ni * 16 + l15] =
            acc[mi][ni][r] + bv_;
    }
  __syncthreads();
  for (int r2 = 0; r2 < 16; ++r2) {
    int c = r2 * 256 + tid;
    int row = c >> 5, j = c & 31;
    *(float4*)(out + (size_t)(m0 + row) * DIM + n0 + j * 4) =
        *(const float4*)(epi + row * FSTR + j * 4);
  }
}

extern "C" void kernel_launch(void* const* d_in, const int* in_sizes, int n_in,
                              void* d_out, int out_size, void* d_ws, size_t ws_size,
                              hipStream_t stream) {
  const float* query = (const float*)d_in[0];
  const float* key   = (const float*)d_in[1];
  const float* value = (const float*)d_in[2];
  const int*   mask  = (const int*)d_in[3];
  const float* wq = (const float*)d_in[4];
  const float* bq = (const float*)d_in[5];
  const float* wk = (const float*)d_in[6];
  const float* bk = (const float*)d_in[7];
  const float* wv = (const float*)d_in[8];
  const float* bv = (const float*)d_in[9];
  const float* wo = (const float*)d_in[10];
  const float* bo = (const float*)d_in[11];
  float* out = (float*)d_out;

  char* ws = (char*)d_ws;
  const size_t SZA = (size_t)NA * 2;  // 8 MiB bf16 activation
  const size_t SZW = (size_t)NW * 2;  // 2 MiB bf16 weight
  __hip_bfloat16* xq  = (__hip_bfloat16*)(ws);
  __hip_bfloat16* xk  = (__hip_bfloat16*)(ws + SZA);
  __hip_bfloat16* xv  = (__hip_bfloat16*)(ws + 2 * SZA);
  __hip_bfloat16* wqb = (__hip_bfloat16*)(ws + 3 * SZA);
  __hip_bfloat16* wkb = (__hip_bfloat16*)(ws + 3 * SZA + SZW);
  __hip_bfloat16* wvb = (__hip_bfloat16*)(ws + 3 * SZA + 2 * SZW);
  __hip_bfloat16* wob = (__hip_bfloat16*)(ws + 3 * SZA + 3 * SZW);
  __hip_bfloat16* q_ws  = (__hip_bfloat16*)(ws + 3 * SZA + 4 * SZW);
  __hip_bfloat16* k_ws  = (__hip_bfloat16*)(ws + 4 * SZA + 4 * SZW);
  __hip_bfloat16* vt_ws = (__hip_bfloat16*)(ws + 5 * SZA + 4 * SZW);
  float* biasg = (float*)(ws + 6 * SZA + 4 * SZW);  // 16 KB
  __hip_bfloat16* ctx_ws = xq;  // xq dead after qkv_proj

  cvt_kernel<<<dim3(8193), dim3(256), 0, stream>>>(
      query, key, value, wq, wk, wv, wo, mask,
      xq, xk, xv, wqb, wkb, wvb, wob, biasg);
  qkv_proj_kernel<<<dim3(8, 32, 3), dim3(256), 0, stream>>>(
      xq, xk, xv, wqb, wkb, wvb, bq, bk, bv, q_ws, k_ws, vt_ws);
  attn_kernel<<<dim3(16, 32), dim3(512), 0, stream>>>(
      q_ws, k_ws, vt_ws, mask, biasg, ctx_ws);
  out_proj_kernel<<<dim3(8, 32), dim3(256), 0, stream>>>(ctx_ws, wob, bo, out);
}